// Round 4
// baseline (483.862 us; speedup 1.0000x reference)
//
#include <hip/hip_runtime.h>
#include <math.h>

// CRF LLH, B=512,S=512,C=96.  Pairing scheme (validated R3):
//   pair t (steps 2t+1, 2t+2):  w <- (w . G_t) * diag(e^{em[2t+2]})
//   G_t = T . diag(e^{em[2t+1]}) . T   (state-independent)
// Changes vs R3 (which passed, absmax 0):
//  * exp(em) precomputed ONCE into d_ws as fp16 (separate memory-bound
//    kernel); producers load 48B/pair instead of 96B + 24 expf.
//  * G layout: column stride 208B (52 dwords == 20 mod 32) -> consumer
//    ds_read_b128 hits 8 disjoint bank-quads per 8 lanes (optimal phases,
//    no swizzle ALU, plain immediate offsets).
//  * consumer lanes 0..47 own columns {l, l+48}; lanes 48..63 idle
//    (R3 duplicated columns -> +33% LDS traffic).
//  * setprio(1) around consumer dot (consumer is the serial path).
// Fragment maps and barrier protocol identical to R3 (validated).

#define BATCH 512
#define SEQ   512
#define NC    96
#define NTHR  256
#define CBYTES 208
#define GBYTES (NC * CBYTES)     // 19968 B per matrix
#define LN2   0.69314718055994531f

typedef __fp16 half2v __attribute__((ext_vector_type(2)));
typedef __fp16 half8  __attribute__((ext_vector_type(8)));
typedef float  f32x4  __attribute__((ext_vector_type(4)));
typedef unsigned int uint2v __attribute__((ext_vector_type(2)));
typedef unsigned int uint4v __attribute__((ext_vector_type(4)));

#define BARRIER() asm volatile("s_waitcnt lgkmcnt(0)\n\ts_barrier" ::: "memory")

#define DPP_STEP_F(v, op, ctrl)                                              \
    v = op(v, __int_as_float(__builtin_amdgcn_update_dpp(                    \
            __float_as_int(v), __float_as_int(v), (ctrl), 0xf, 0xf, false)))

__device__ __forceinline__ float fadd_(float a, float b) { return a + b; }
__device__ __forceinline__ float wave_sum_all(float v) {
    DPP_STEP_F(v, fadd_, 0x111);
    DPP_STEP_F(v, fadd_, 0x112);
    DPP_STEP_F(v, fadd_, 0x114);
    DPP_STEP_F(v, fadd_, 0x118);
    DPP_STEP_F(v, fadd_, 0x142);
    DPP_STEP_F(v, fadd_, 0x143);
    return __int_as_float(__builtin_amdgcn_readlane(__float_as_int(v), 63));
}
__device__ __forceinline__ float wave_max_all(float v) {
    DPP_STEP_F(v, fmaxf, 0x111);
    DPP_STEP_F(v, fmaxf, 0x112);
    DPP_STEP_F(v, fmaxf, 0x114);
    DPP_STEP_F(v, fmaxf, 0x118);
    DPP_STEP_F(v, fmaxf, 0x142);
    DPP_STEP_F(v, fmaxf, 0x143);
    return __int_as_float(__builtin_amdgcn_readlane(__float_as_int(v), 63));
}

__device__ __forceinline__ unsigned pk2(float a, float b) {
    return __builtin_bit_cast(unsigned, __builtin_amdgcn_cvt_pkrtz(a, b));
}
__device__ __forceinline__ half2v bch(unsigned u) { return __builtin_bit_cast(half2v, u); }
__device__ __forceinline__ float fdot2_(unsigned a, unsigned b, float c) {
    return __builtin_amdgcn_fdot2(bch(a), bch(b), c, false);
}
__device__ __forceinline__ half8 h8(uint4v u) { return __builtin_bit_cast(half8, u); }
__device__ __forceinline__ half8 exp8(float4 u, float4 v) {
    uint4v r;
    r.x = pk2(__expf(u.x), __expf(u.y));
    r.y = pk2(__expf(u.z), __expf(u.w));
    r.z = pk2(__expf(v.x), __expf(v.y));
    r.w = pk2(__expf(v.z), __expf(v.w));
    return __builtin_bit_cast(half8, r);
}

// dual-column dot: cols (l, l+48), column stride CBYTES
__device__ __forceinline__ void coldot2(const char* colbase, const uint4v* sv,
                                        float& u0, float& u1) {
    float a0 = 0.f, a1 = 0.f, a2 = 0.f, a3 = 0.f;
    float b0 = 0.f, b1 = 0.f, b2 = 0.f, b3 = 0.f;
    #pragma unroll
    for (int q = 0; q < 12; ++q) {
        const uint4v x = *(const uint4v*)(colbase + 16 * q);
        const uint4v y = *(const uint4v*)(colbase + 48 * CBYTES + 16 * q);
        const uint4v s = sv[q];
        a0 = fdot2_(s.x, x.x, a0); a1 = fdot2_(s.y, x.y, a1);
        a2 = fdot2_(s.z, x.z, a2); a3 = fdot2_(s.w, x.w, a3);
        b0 = fdot2_(s.x, y.x, b0); b1 = fdot2_(s.y, y.y, b1);
        b2 = fdot2_(s.z, y.z, b2); b3 = fdot2_(s.w, y.w, b3);
    }
    u0 = (a0 + a1) + (a2 + a3);
    u1 = (b0 + b1) + (b2 + b3);
}

__global__ __launch_bounds__(256)
void exp_pre_kernel(const float* __restrict__ em, __fp16* __restrict__ ex) {
    const size_t i = ((size_t)blockIdx.x * 256 + threadIdx.x) * 8;
    const float4 a = *(const float4*)(em + i);
    const float4 b = *(const float4*)(em + i + 4);
    uint4v r;
    r.x = pk2(__expf(a.x), __expf(a.y));
    r.y = pk2(__expf(a.z), __expf(a.w));
    r.z = pk2(__expf(b.x), __expf(b.y));
    r.w = pk2(__expf(b.z), __expf(b.w));
    *(uint4v*)(ex + i) = r;
}

template<int UEX>
__global__ __launch_bounds__(NTHR, 2)
void crf_pair2_kernel(const float* __restrict__ em,      // (B,S,C)
                      const int*   __restrict__ tags,    // (B,S)
                      const int*   __restrict__ masks,   // (B,S)
                      const float* __restrict__ startT,  // (C)
                      const float* __restrict__ endT,    // (C)
                      const float* __restrict__ trans,   // (C,C)
                      const __fp16* __restrict__ exq,    // fp16 exp(em) or null
                      float*       __restrict__ out)     // scalar
{
    const int tid = threadIdx.x;
    const int l   = tid & 63;
    const int w   = tid >> 6;
    const int b   = blockIdx.x;

    __shared__ __align__(16) char  GBm[2][GBYTES];  // pair-matrix double buffer
    __shared__ __align__(16) char  EBm[GBYTES];     // resident E
    __shared__ __align__(16) __fp16 ST[96];         // state

    const float*  em_b    = em    + (size_t)b * SEQ * NC;
    const int*    masks_b = masks + (size_t)b * SEQ;
    const __fp16* exq_b   = UEX ? (exq + (size_t)b * SEQ * NC) : (const __fp16*)0;

    if (w == 0) {
        // ===================== consumer =====================
        const bool act = (l < 48);

        float s0 = -1e30f, s1 = -1e30f;
        if (act) {
            s0 = startT[l]      + em_b[l];
            s1 = startT[l + 48] + em_b[l + 48];
        }
        const float M0 = wave_max_all(fmaxf(s0, s1));
        if (act) {
            ST[l]      = (__fp16)__expf(s0 - M0);
            ST[l + 48] = (__fp16)__expf(s1 - M0);
        }
        int sk = 0;

        auto ldE = [&](int row, float& x0, float& x1) {
            if (act) {
                if (UEX) {
                    x0 = (float)exq_b[(size_t)row * NC + l];
                    x1 = (float)exq_b[(size_t)row * NC + l + 48];
                } else {
                    x0 = __expf(em_b[(size_t)row * NC + l]);
                    x1 = __expf(em_b[(size_t)row * NC + l + 48]);
                }
            } else { x0 = 0.f; x1 = 0.f; }
        };

        auto sstep = [&](int row) {   // cold single step vs resident E
            uint4v sv[12];
            const uint4v* stp = (const uint4v*)ST;
            #pragma unroll
            for (int q = 0; q < 12; ++q) sv[q] = stp[q];
            float v0 = 0.f, v1 = 0.f;
            if (act) coldot2((const char*)EBm + l * CBYTES, sv, v0, v1);
            if (act) {
                v0 *= __expf(em_b[(size_t)row * NC + l]);
                v1 *= __expf(em_b[(size_t)row * NC + l + 48]);
            }
            const float mx = wave_max_all(fmaxf(v0, v1));
            const unsigned ebx = (__float_as_uint(mx) >> 23) & 255u;
            sk += (int)ebx - 127;
            const float sc = __uint_as_float((254u - ebx) << 23);
            if (act) {
                ST[l]      = (__fp16)(v0 * sc);
                ST[l + 48] = (__fp16)(v1 * sc);
            }
        };

        auto body = [&](int t, float e0, float e1, int mk) {
            BARRIER();                               // G[t] ready in GBm[t&1]
            uint4v sv[12];
            const uint4v* stp = (const uint4v*)ST;
            #pragma unroll
            for (int q = 0; q < 12; ++q) sv[q] = stp[q];
            float u0 = 0.f, u1 = 0.f;
            __builtin_amdgcn_s_setprio(1);
            if (act) coldot2((const char*)GBm[t & 1] + l * CBYTES, sv, u0, u1);
            __builtin_amdgcn_s_setprio(0);
            if (mk == 3) {
                u0 *= e0; u1 *= e1;
                const float mx = wave_max_all(fmaxf(u0, u1));
                const unsigned ebx = (__float_as_uint(mx) >> 23) & 255u;
                sk += (int)ebx - 127;
                const float sc = __uint_as_float((254u - ebx) << 23);
                if (act) {
                    ST[l]      = (__fp16)(u0 * sc);
                    ST[l + 48] = (__fp16)(u1 * sc);
                }
            } else {                                  // cold (masked) path
                if (mk & 1) sstep(2 * t + 1);
                if (mk & 2) sstep(2 * t + 2);
            }
        };

        float eA0, eA1, eB0, eB1;
        ldE(2, eA0, eA1);
        int mkA = (masks_b[1] ? 1 : 0) | (masks_b[2] ? 2 : 0);
        ldE(4, eB0, eB1);
        int mkB = (masks_b[3] ? 1 : 0) | (masks_b[4] ? 2 : 0);

        #pragma unroll 1
        for (int t = 0; t < 254; t += 2) {
            body(t, eA0, eA1, mkA);
            {
                const int rb = 2 * t + 6;            // <= 510
                ldE(rb, eA0, eA1);
                mkA = (masks_b[2 * t + 5] ? 1 : 0) | (masks_b[rb] ? 2 : 0);
            }
            body(t + 1, eB0, eB1, mkB);
            {
                const int ra = 2 * t + 7;            // <= 511
                const int rb = (2 * t + 8 > 511) ? 511 : (2 * t + 8);
                ldE(rb, eB0, eB1);
                mkB = (masks_b[ra] ? 1 : 0) | (masks_b[rb] ? 2 : 0);
            }
        }
        body(254, eA0, eA1, mkA);

        // ---- final single step s=511 vs resident E, then denominator
        {
            uint4v sv[12];
            const uint4v* stp = (const uint4v*)ST;
            #pragma unroll
            for (int q = 0; q < 12; ++q) sv[q] = stp[q];
            float u0 = 0.f, u1 = 0.f;
            if (act) coldot2((const char*)EBm + l * CBYTES, sv, u0, u1);
            float w0 = 0.f, w1 = 0.f;
            if (act) {
                if (masks_b[511]) {
                    u0 *= __expf(em_b[(size_t)511 * NC + l]);
                    u1 *= __expf(em_b[(size_t)511 * NC + l + 48]);
                } else {
                    u0 = (float)ST[l];
                    u1 = (float)ST[l + 48];
                }
                w0 = u0 * __expf(endT[l]);
                w1 = u1 * __expf(endT[l + 48]);
            }
            const float dv = wave_sum_all(w0 + w1);
            if (l == 0)
                atomicAdd(out, -(M0 + (float)sk * LN2 + __logf(dv)) * (1.0f / (float)BATCH));
        }
    } else {
        // ===================== producers =====================
        const int lidx = l & 15;
        const int g    = l >> 4;
        const int nt0  = 2 * (w - 1);    // two 16-col tiles per wave

        half8 Ea[6][3];
        #pragma unroll
        for (int r = 0; r < 6; ++r)
            #pragma unroll
            for (int c = 0; c < 3; ++c) {
                half8 v;
                #pragma unroll
                for (int e = 0; e < 8; ++e)
                    v[e] = (__fp16)__expf(trans[(16 * r + lidx) * NC + 32 * c + 8 * g + e]);
                Ea[r][c] = v;
            }
        half8 Eb[3][2];
        #pragma unroll
        for (int c = 0; c < 3; ++c)
            #pragma unroll
            for (int ntL = 0; ntL < 2; ++ntL) {
                half8 v;
                #pragma unroll
                for (int e = 0; e < 8; ++e)
                    v[e] = (__fp16)__expf(trans[(32 * c + 8 * g + e) * NC + 16 * (nt0 + ntL) + lidx]);
                Eb[c][ntL] = v;
            }
        // resident E, col stride CBYTES; chunk (4c+g) holds k=32c+8g..+7
        #pragma unroll
        for (int ntL = 0; ntL < 2; ++ntL)
            #pragma unroll
            for (int c = 0; c < 3; ++c)
                *(uint4v*)(EBm + (16 * (nt0 + ntL) + lidx) * CBYTES + (4 * c + g) * 16) =
                    __builtin_bit_cast(uint4v, Eb[c][ntL]);

        auto build = [&](int bsel, half8 d0, half8 d1, half8 d2) {
            half8 bw[3][2];
            #pragma unroll
            for (int ntL = 0; ntL < 2; ++ntL) {
                bw[0][ntL] = Eb[0][ntL] * d0;
                bw[1][ntL] = Eb[1][ntL] * d1;
                bw[2][ntL] = Eb[2][ntL] * d2;
            }
            char* dst = GBm[bsel];
            #pragma unroll
            for (int ntL = 0; ntL < 2; ++ntL) {
                char* cp = dst + (16 * (nt0 + ntL) + lidx) * CBYTES
                               + 16 * (g >> 1) + 8 * (g & 1);
                #pragma unroll
                for (int r = 0; r < 6; ++r) {
                    const f32x4 z = {0.f, 0.f, 0.f, 0.f};
                    f32x4 acc = __builtin_amdgcn_mfma_f32_16x16x32_f16(Ea[r][0], bw[0][ntL], z, 0, 0, 0);
                    acc = __builtin_amdgcn_mfma_f32_16x16x32_f16(Ea[r][1], bw[1][ntL], acc, 0, 0, 0);
                    acc = __builtin_amdgcn_mfma_f32_16x16x32_f16(Ea[r][2], bw[2][ntL], acc, 0, 0, 0);
                    uint2v wv;
                    wv.x = pk2(acc[0], acc[1]);
                    wv.y = pk2(acc[2], acc[3]);
                    *(uint2v*)(cp + 32 * r) = wv;
                }
            }
        };

        if (UEX) {
            auto ld3 = [&](int row, uint4v& a, uint4v& bq, uint4v& c) {
                const char* p = (const char*)exq_b + (size_t)row * 192 + 16 * g;
                a  = *(const uint4v*)(p);
                bq = *(const uint4v*)(p + 64);
                c  = *(const uint4v*)(p + 128);
            };
            {
                uint4v a, bq, c;
                ld3(1, a, bq, c);
                build(0, h8(a), h8(bq), h8(c));
            }
            uint4v p0a, p0b, p0c, p1a, p1b, p1c;
            ld3(3, p0a, p0b, p0c);
            ld3(5, p1a, p1b, p1c);
            #pragma unroll 1
            for (int t = 0; t < 254; t += 2) {
                BARRIER();
                build(1, h8(p0a), h8(p0b), h8(p0c));
                { const int rr = 2 * t + 7; ld3(rr > 511 ? 511 : rr, p0a, p0b, p0c); }
                BARRIER();
                build(0, h8(p1a), h8(p1b), h8(p1c));
                { const int rr = 2 * t + 9; ld3(rr > 511 ? 511 : rr, p1a, p1b, p1c); }
            }
            BARRIER();
        } else {
            auto ld6 = [&](int row, float4& x0, float4& x1, float4& x2,
                           float4& x3, float4& x4, float4& x5) {
                const float* p = em_b + (size_t)row * NC + 8 * g;
                x0 = *(const float4*)(p);      x1 = *(const float4*)(p + 4);
                x2 = *(const float4*)(p + 32); x3 = *(const float4*)(p + 36);
                x4 = *(const float4*)(p + 64); x5 = *(const float4*)(p + 68);
            };
            {
                float4 x0, x1, x2, x3, x4, x5;
                ld6(1, x0, x1, x2, x3, x4, x5);
                build(0, exp8(x0, x1), exp8(x2, x3), exp8(x4, x5));
            }
            float4 a0, a1, a2, a3, a4, a5, b0, b1, b2, b3, b4, b5;
            ld6(3, a0, a1, a2, a3, a4, a5);
            ld6(5, b0, b1, b2, b3, b4, b5);
            #pragma unroll 1
            for (int t = 0; t < 254; t += 2) {
                BARRIER();
                build(1, exp8(a0, a1), exp8(a2, a3), exp8(a4, a5));
                { const int rr = 2 * t + 7; ld6(rr > 511 ? 511 : rr, a0, a1, a2, a3, a4, a5); }
                BARRIER();
                build(0, exp8(b0, b1), exp8(b2, b3), exp8(b4, b5));
                { const int rr = 2 * t + 9; ld6(rr > 511 ? 511 : rr, b0, b1, b2, b3, b4, b5); }
            }
            BARRIER();
        }

        // ---- numerator on wave 1 (tag-path gather for this chain)
        if (w == 1) {
            const int* tb = tags + (size_t)b * SEQ;
            float nsum = 0.f, msum = 0.f;
            #pragma unroll
            for (int kk = 0; kk < 8; ++kk) {
                const int s  = l + 64 * kk;
                const int tg = tb[s];
                const int mk = masks_b[s];
                msum += mk ? 1.f : 0.f;
                if (s == 0) {
                    nsum += startT[tg] + em_b[tg];
                } else if (mk) {
                    nsum += trans[tb[s - 1] * NC + tg] + em_b[(size_t)s * NC + tg];
                }
            }
            nsum = wave_sum_all(nsum);
            msum = wave_sum_all(msum);
            if (l == 0) {
                const int cnt  = (int)msum;
                const int last = tb[cnt - 1];
                atomicAdd(out, (nsum + endT[last]) * (1.0f / (float)BATCH));
            }
        }
    }
}

extern "C" void kernel_launch(void* const* d_in, const int* in_sizes, int n_in,
                              void* d_out, int out_size, void* d_ws, size_t ws_size,
                              hipStream_t stream) {
    const float* em     = (const float*)d_in[0];
    const int*   tags   = (const int*)  d_in[1];
    const int*   masks  = (const int*)  d_in[2];
    const float* startT = (const float*)d_in[3];
    const float* endT   = (const float*)d_in[4];
    const float* trans  = (const float*)d_in[5];
    float* out = (float*)d_out;

    (void)hipMemsetAsync(out, 0, sizeof(float), stream);

    const size_t exbytes = (size_t)BATCH * SEQ * NC * sizeof(__fp16);
    if (d_ws != nullptr && ws_size >= exbytes) {
        const int nelem8 = BATCH * SEQ * NC / 8;          // 3145728
        exp_pre_kernel<<<nelem8 / 256, 256, 0, stream>>>(em, (__fp16*)d_ws);
        crf_pair2_kernel<1><<<BATCH, NTHR, 0, stream>>>(
            em, tags, masks, startT, endT, trans, (const __fp16*)d_ws, out);
    } else {
        crf_pair2_kernel<0><<<BATCH, NTHR, 0, stream>>>(
            em, tags, masks, startT, endT, trans, (const __fp16*)0, out);
    }
}